// Round 2
// baseline (547.508 us; speedup 1.0000x reference)
//
#include <hip/hip_runtime.h>

#define N_DIM 32
#define C_IN 64
#define C_OUT 64
#define T_DIM 288
#define V_DIM 25
#define TV 7200              // T_DIM * V_DIM
#define NTV 230400           // N_DIM * TV  (BN reduction count per channel)
#define TOTAL 14745600       // N_DIM * C_OUT * TV
#define BN_EPS 1e-5f

// ws layout (float offsets)
#define WS_WINT 0            // wint[c][half][oo][2] : 64*2*32*2 = 8192 floats
#define WS_SUM 8192          // gsum[64]
#define WS_SQ  8256          // gsumsq[64]

// ---------------------------------------------------------------- K0: prep
__global__ __launch_bounds__(256) void prep_kernel(const float* __restrict__ W,
                                                   float* __restrict__ ws) {
  const int tid = threadIdx.x;
  if (tid < 128) ws[WS_SUM + tid] = 0.0f;     // zero sum + sumsq
  for (int i = tid; i < 8192; i += 256) {
    // i = (((c*2 + half)*32 + oo)*2 + s)
    const int s = i & 1;
    const int oo = (i >> 1) & 31;
    const int half = (i >> 6) & 1;
    const int c = i >> 7;
    const int o = half * 32 + oo;
    ws[WS_WINT + i] = W[o * 128 + s * 64 + c];  // s=0: fv weight, s=1: agg weight
  }
}

// butterfly-transpose reduce: v[32] per lane (destroyed); returns, on every
// lane, the sum of value index (lane&31) across the lane's 32-lane half.
__device__ __forceinline__ float reduce32_lane(float* v, int lane) {
#pragma unroll
  for (int s = 0; s < 5; ++s) {
    const int m = 1 << s;
    const bool up = (lane & m) != 0;
    const int pairs = 32 >> (s + 1);
#pragma unroll
    for (int q = 0; q < pairs; ++q) {
      const float keep = up ? v[2 * q + 1] : v[2 * q];
      const float send = up ? v[2 * q] : v[2 * q + 1];
      const float recv = __shfl_xor(send, m, 64);
      v[q] = keep + recv;
    }
  }
  return v[0];
}

// ---------------------------------------------------------------- K1: main
// 256 threads = 128 columns x 2 channel-halves. Each thread: 32 outputs.
__global__ __launch_bounds__(256) void main_kernel(const float* __restrict__ fv,
                                                   const float* __restrict__ adj,
                                                   const float* __restrict__ wint,
                                                   float* __restrict__ stats,
                                                   float* __restrict__ out) {
  __shared__ float lsum[C_OUT];
  __shared__ float lsq[C_OUT];
  const int tid = threadIdx.x;
  if (tid < 64) lsum[tid] = 0.0f;
  else if (tid < 128) lsq[tid - 64] = 0.0f;
  __syncthreads();

  const int half = tid >> 7;                    // 0: channels 0-31, 1: 32-63
  const int col = (blockIdx.x << 7) + (tid & 127);  // 0 .. NTV-1 (exact grid)
  const int lane = tid & 63;

  const int n = col / TV;
  const int r = col - n * TV;
  const int t = r / V_DIM;
  const int y = r - t * V_DIM;

  float adjcol[V_DIM];
#pragma unroll
  for (int v = 0; v < V_DIM; ++v) adjcol[v] = adj[v * V_DIM + y];

  const float* base = fv + (size_t)n * (C_IN * TV) + t * V_DIM;
  const float* wbase = wint + half * 64;        // uniform within each wave

  float acc[32];
#pragma unroll
  for (int oo = 0; oo < 32; ++oo) acc[oo] = 0.0f;

  for (int c = 0; c < C_IN; ++c) {
    const float* p = base + c * TV;
    const float x = p[y];
    float xa0 = 0.f, xa1 = 0.f, xa2 = 0.f, xa3 = 0.f;
#pragma unroll
    for (int v = 0; v < 24; v += 4) {
      xa0 = fmaf(p[v + 0], adjcol[v + 0], xa0);
      xa1 = fmaf(p[v + 1], adjcol[v + 1], xa1);
      xa2 = fmaf(p[v + 2], adjcol[v + 2], xa2);
      xa3 = fmaf(p[v + 3], adjcol[v + 3], xa3);
    }
    xa0 = fmaf(p[24], adjcol[24], xa0);
    const float xa = (xa0 + xa1) + (xa2 + xa3);

    // 64 contiguous, wave-uniform floats -> s_load + SGPR-operand fma
    const float* __restrict__ w = wbase + c * 128;
#pragma unroll
    for (int oo = 0; oo < 32; ++oo)
      acc[oo] = fmaf(x, w[oo * 2], fmaf(xa, w[oo * 2 + 1], acc[oo]));
  }

  // write pre-BN output (channels half*32 .. half*32+31)
  float* op = out + (size_t)n * (C_OUT * TV) + (size_t)(half * 32) * TV
              + t * V_DIM + y;
#pragma unroll
  for (int oo = 0; oo < 32; ++oo) op[oo * TV] = acc[oo];

  // per-wave channel sums / sumsq -> LDS -> one global atomic set per block
  float sq[32];
#pragma unroll
  for (int i = 0; i < 32; ++i) sq[i] = acc[i] * acc[i];
  float s = reduce32_lane(acc, lane);           // destroys acc
  s += __shfl_xor(s, 32, 64);
  float q = reduce32_lane(sq, lane);
  q += __shfl_xor(q, 32, 64);

  if (lane < 32) {
    atomicAdd(&lsum[half * 32 + lane], s);
    atomicAdd(&lsq[half * 32 + lane], q);
  }
  __syncthreads();
  if (tid < 64) {
    atomicAdd(&stats[tid], lsum[tid]);
    atomicAdd(&stats[64 + tid], lsq[tid]);
  }
}

// ---------------------------------------------------------------- K2: BN+ReLU
__global__ __launch_bounds__(256) void bn_kernel(const float* __restrict__ stats,
                                                 const float* __restrict__ gamma,
                                                 const float* __restrict__ beta,
                                                 float* __restrict__ out) {
  __shared__ float s_scale[C_OUT];
  __shared__ float s_shift[C_OUT];
  const int tid = threadIdx.x;
  if (tid < C_OUT) {
    const float inv = 1.0f / (float)NTV;
    const float mean = stats[tid] * inv;
    const float var = fmaf(stats[64 + tid], inv, -mean * mean);
    const float sc = gamma[tid] * rsqrtf(var + BN_EPS);
    s_scale[tid] = sc;
    s_shift[tid] = fmaf(-mean, sc, beta[tid]);
  }
  __syncthreads();

  float4* o4 = reinterpret_cast<float4*>(out);
  const int total4 = TOTAL / 4;               // TV%4==0 so channel is
  const int stride = gridDim.x * blockDim.x;  // constant within each float4
  for (int i = blockIdx.x * blockDim.x + tid; i < total4; i += stride) {
    float4 v = o4[i];
    const int o = (i / 1800) & 63;            // 1800 = TV/4
    const float sc = s_scale[o];
    const float sh = s_shift[o];
    v.x = fmaxf(fmaf(v.x, sc, sh), 0.0f);
    v.y = fmaxf(fmaf(v.y, sc, sh), 0.0f);
    v.z = fmaxf(fmaf(v.z, sc, sh), 0.0f);
    v.w = fmaxf(fmaf(v.w, sc, sh), 0.0f);
    o4[i] = v;
  }
}

// ---------------------------------------------------------------- launcher
extern "C" void kernel_launch(void* const* d_in, const int* in_sizes, int n_in,
                              void* d_out, int out_size, void* d_ws, size_t ws_size,
                              hipStream_t stream) {
  const float* fv = (const float*)d_in[0];
  const float* adj = (const float*)d_in[1];
  const float* W = (const float*)d_in[2];
  // d_in[3] = b : exactly cancelled by training-mode BN mean subtraction
  const float* gamma = (const float*)d_in[4];
  const float* beta = (const float*)d_in[5];
  float* out = (float*)d_out;
  float* ws = (float*)d_ws;

  hipLaunchKernelGGL(prep_kernel, dim3(1), dim3(256), 0, stream, W, ws);
  hipLaunchKernelGGL(main_kernel, dim3(NTV / 128), dim3(256), 0, stream,
                     fv, adj, ws + WS_WINT, ws + WS_SUM, out);
  hipLaunchKernelGGL(bn_kernel, dim3(2048), dim3(256), 0, stream,
                     ws + WS_SUM, gamma, beta, out);
}

// Round 3
// 259.676 us; speedup vs baseline: 2.1084x; 2.1084x over previous
//
#include <hip/hip_runtime.h>

#define N_DIM 32
#define C_IN 64
#define C_OUT 64
#define T_DIM 288
#define V_DIM 25
#define TV 7200              // T_DIM * V_DIM
#define NTV 230400           // N_DIM * TV  (BN reduction count per channel)
#define TOTAL 14745600       // N_DIM * C_OUT * TV
#define BN_EPS 1e-5f

// ws layout (float offsets)
#define WS_WINT 0            // wint[half][c][oo][2] : 2*64*32*2 = 8192 floats
#define WS_SUM 8192          // gsum[64]
#define WS_SQ  8256          // gsumsq[64]

// ---------------------------------------------------------------- K0: prep
__global__ __launch_bounds__(256) void prep_kernel(const float* __restrict__ W,
                                                   float* __restrict__ ws) {
  const int tid = threadIdx.x;
  if (tid < 128) ws[WS_SUM + tid] = 0.0f;     // zero sum + sumsq
  for (int i = tid; i < 8192; i += 256) {
    // i = ((h*64 + c)*32 + oo)*2 + s
    const int s = i & 1;
    const int oo = (i >> 1) & 31;
    const int c = (i >> 6) & 63;
    const int h = i >> 12;
    const int o = h * 32 + oo;
    ws[WS_WINT + i] = W[o * 128 + s * 64 + c];  // s=0: fv weight, s=1: agg weight
  }
}

// butterfly-transpose reduce: v[32] per lane (destroyed); returns, on every
// lane, the sum of value index (lane&31) across the lane's 32-lane half.
__device__ __forceinline__ float reduce32_lane(float* v, int lane) {
#pragma unroll
  for (int s = 0; s < 5; ++s) {
    const int m = 1 << s;
    const bool up = (lane & m) != 0;
    const int pairs = 32 >> (s + 1);
#pragma unroll
    for (int q = 0; q < pairs; ++q) {
      const float keep = up ? v[2 * q + 1] : v[2 * q];
      const float send = up ? v[2 * q] : v[2 * q + 1];
      const float recv = __shfl_xor(send, m, 64);
      v[q] = keep + recv;
    }
  }
  return v[0];
}

// ---------------------------------------------------------------- K1: main
// 256 threads = 128 columns x 2 channel-halves. Each thread: 32 outputs.
__global__ __launch_bounds__(256) void main_kernel(const float* __restrict__ fv,
                                                   const float* __restrict__ adj,
                                                   const float* __restrict__ wint,
                                                   float* __restrict__ stats,
                                                   float* __restrict__ out) {
  __shared__ float lsum[C_OUT];
  __shared__ float lsq[C_OUT];
  const int tid = threadIdx.x;
  if (tid < 64) lsum[tid] = 0.0f;
  else if (tid < 128) lsq[tid - 64] = 0.0f;
  __syncthreads();

  // WAVE-UNIFORM channel-half selector: readfirstlane puts it in an SGPR so
  // the weight address stays scalar -> s_load_dwordx16 (the R2 regression was
  // losing this).
  const int half = __builtin_amdgcn_readfirstlane(tid) >> 7;
  const int col = (blockIdx.x << 7) + (tid & 127);  // 0 .. NTV-1 (exact grid)
  const int lane = tid & 63;

  const int n = col / TV;
  const int r = col - n * TV;
  const int t = r / V_DIM;
  const int y = r - t * V_DIM;

  float adjcol[V_DIM];
#pragma unroll
  for (int v = 0; v < V_DIM; ++v) adjcol[v] = adj[v * V_DIM + y];

  const float* base = fv + (size_t)n * (C_IN * TV) + t * V_DIM;
  const float* __restrict__ wbase = wint + half * 4096;  // scalar pointer

  float acc[32];
#pragma unroll
  for (int oo = 0; oo < 32; ++oo) acc[oo] = 0.0f;

  for (int c = 0; c < C_IN; ++c) {
    const float* p = base + c * TV;
    const float x = p[y];
    float xa0 = 0.f, xa1 = 0.f, xa2 = 0.f, xa3 = 0.f;
#pragma unroll
    for (int v = 0; v < 24; v += 4) {
      xa0 = fmaf(p[v + 0], adjcol[v + 0], xa0);
      xa1 = fmaf(p[v + 1], adjcol[v + 1], xa1);
      xa2 = fmaf(p[v + 2], adjcol[v + 2], xa2);
      xa3 = fmaf(p[v + 3], adjcol[v + 3], xa3);
    }
    xa0 = fmaf(p[24], adjcol[24], xa0);
    const float xa = (xa0 + xa1) + (xa2 + xa3);

    // 64 contiguous wave-uniform floats -> 4x s_load_dwordx16, SGPR-operand fma
    const float* __restrict__ w = wbase + c * 64;
#pragma unroll
    for (int oo = 0; oo < 32; ++oo)
      acc[oo] = fmaf(x, w[oo * 2], fmaf(xa, w[oo * 2 + 1], acc[oo]));
  }

  // write pre-BN output (channels half*32 .. half*32+31)
  float* op = out + (size_t)n * (C_OUT * TV) + (size_t)(half * 32) * TV
              + t * V_DIM + y;
#pragma unroll
  for (int oo = 0; oo < 32; ++oo) op[oo * TV] = acc[oo];

  // per-wave channel sums / sumsq -> LDS -> one global atomic set per block
  float sq[32];
#pragma unroll
  for (int i = 0; i < 32; ++i) sq[i] = acc[i] * acc[i];
  float s = reduce32_lane(acc, lane);           // destroys acc
  s += __shfl_xor(s, 32, 64);
  float q = reduce32_lane(sq, lane);
  q += __shfl_xor(q, 32, 64);

  if (lane < 32) {
    atomicAdd(&lsum[half * 32 + lane], s);
    atomicAdd(&lsq[half * 32 + lane], q);
  }
  __syncthreads();
  if (tid < 64) {
    atomicAdd(&stats[tid], lsum[tid]);
    atomicAdd(&stats[64 + tid], lsq[tid]);
  }
}

// ---------------------------------------------------------------- K2: BN+ReLU
__global__ __launch_bounds__(256) void bn_kernel(const float* __restrict__ stats,
                                                 const float* __restrict__ gamma,
                                                 const float* __restrict__ beta,
                                                 float* __restrict__ out) {
  __shared__ float s_scale[C_OUT];
  __shared__ float s_shift[C_OUT];
  const int tid = threadIdx.x;
  if (tid < C_OUT) {
    const float inv = 1.0f / (float)NTV;
    const float mean = stats[tid] * inv;
    const float var = fmaf(stats[64 + tid], inv, -mean * mean);
    const float sc = gamma[tid] * rsqrtf(var + BN_EPS);
    s_scale[tid] = sc;
    s_shift[tid] = fmaf(-mean, sc, beta[tid]);
  }
  __syncthreads();

  float4* o4 = reinterpret_cast<float4*>(out);
  const int total4 = TOTAL / 4;               // TV%4==0 so channel is
  const int stride = gridDim.x * blockDim.x;  // constant within each float4
  for (int i = blockIdx.x * blockDim.x + tid; i < total4; i += stride) {
    float4 v = o4[i];
    const int o = (i / 1800) & 63;            // 1800 = TV/4
    const float sc = s_scale[o];
    const float sh = s_shift[o];
    v.x = fmaxf(fmaf(v.x, sc, sh), 0.0f);
    v.y = fmaxf(fmaf(v.y, sc, sh), 0.0f);
    v.z = fmaxf(fmaf(v.z, sc, sh), 0.0f);
    v.w = fmaxf(fmaf(v.w, sc, sh), 0.0f);
    o4[i] = v;
  }
}

// ---------------------------------------------------------------- launcher
extern "C" void kernel_launch(void* const* d_in, const int* in_sizes, int n_in,
                              void* d_out, int out_size, void* d_ws, size_t ws_size,
                              hipStream_t stream) {
  const float* fv = (const float*)d_in[0];
  const float* adj = (const float*)d_in[1];
  const float* W = (const float*)d_in[2];
  // d_in[3] = b : exactly cancelled by training-mode BN mean subtraction
  const float* gamma = (const float*)d_in[4];
  const float* beta = (const float*)d_in[5];
  float* out = (float*)d_out;
  float* ws = (float*)d_ws;

  hipLaunchKernelGGL(prep_kernel, dim3(1), dim3(256), 0, stream, W, ws);
  hipLaunchKernelGGL(main_kernel, dim3(NTV / 128), dim3(256), 0, stream,
                     fv, adj, ws + WS_WINT, ws + WS_SUM, out);
  hipLaunchKernelGGL(bn_kernel, dim3(2048), dim3(256), 0, stream,
                     ws + WS_SUM, gamma, beta, out);
}